// Round 3
// 2319.436 us; speedup vs baseline: 1.1211x; 1.1211x over previous
//
#include <hip/hip_runtime.h>
#include <cmath>

typedef unsigned short u16;
typedef short bf16x8 __attribute__((ext_vector_type(8)));
typedef float f32x4 __attribute__((ext_vector_type(4)));
typedef unsigned short u16x8 __attribute__((ext_vector_type(8)));

#define VSZ 50257
#define DM 512
#define NL 4
#define NH 8
#define HDIM 64
#define FFD 2048
#define BB 2
#define SS 2048
#define RR (BB*SS)          // 4096 rows
#define LNEPS 1e-5f

__device__ __forceinline__ u16 f2bf(float f) {
  unsigned u = __float_as_uint(f);
  unsigned r = u + 0x7FFFu + ((u >> 16) & 1u);
  return (u16)(r >> 16);
}

// async 16B global -> LDS (DMA path, no VGPR round trip)
__device__ __forceinline__ void gload16(const void* g, void* l) {
  __builtin_amdgcn_global_load_lds(
      (const __attribute__((address_space(1))) unsigned int*)g,
      (__attribute__((address_space(3))) unsigned int*)l, 16, 0, 0);
}

// ---------------- flat f32 -> bf16 convert ----------------
__global__ void k_convert(const float* __restrict__ in, u16* __restrict__ out, long n) {
  long i = ((long)blockIdx.x * 256 + threadIdx.x) * 8;
  if (i + 8 <= n) {
    float4 a = *(const float4*)(in + i);
    float4 b = *(const float4*)(in + i + 4);
    u16x8 v;
    v[0]=f2bf(a.x); v[1]=f2bf(a.y); v[2]=f2bf(a.z); v[3]=f2bf(a.w);
    v[4]=f2bf(b.x); v[5]=f2bf(b.y); v[6]=f2bf(b.z); v[7]=f2bf(b.w);
    *(u16x8*)(out + i) = v;
  }
}

// ------------- transpose + convert: in [K,N] f32 -> out [N,K] bf16, layer via z -------------
__global__ void k_transpose_convert(const float* __restrict__ in0, u16* __restrict__ out0, int K, int N) {
  const float* in = in0 + (size_t)blockIdx.z * K * N;
  u16* out = out0 + (size_t)blockIdx.z * K * N;
  __shared__ float tile[32][33];
  int tx = threadIdx.x, ty = threadIdx.y;     // (32,8)
  int n0 = blockIdx.x * 32, k0 = blockIdx.y * 32;
  #pragma unroll
  for (int i = 0; i < 4; i++)
    tile[ty + i*8][tx] = in[(size_t)(k0 + ty + i*8) * N + n0 + tx];
  __syncthreads();
  #pragma unroll
  for (int i = 0; i < 4; i++)
    out[(size_t)(n0 + ty + i*8) * K + k0 + tx] = f2bf(tile[tx][ty + i*8]);
}

// ---------------- embedding: x = wte[idx] + wpe[s] ----------------
__global__ void k_embed(const int* __restrict__ idx, const float* __restrict__ wte,
                        const float* __restrict__ wpe, float* __restrict__ x) {
  int r = blockIdx.x;                 // 0..4095
  int s = r & (SS - 1);
  int t = threadIdx.x;                // 0..127 -> 4 floats each
  int tok = idx[r];
  float4 a = *(const float4*)(wte + (size_t)tok * DM + t*4);
  float4 b = *(const float4*)(wpe + (size_t)s * DM + t*4);
  a.x += b.x; a.y += b.y; a.z += b.z; a.w += b.w;
  *(float4*)(x + (size_t)r * DM + t*4) = a;
}

// ---------------- LayerNorm fp32 -> bf16, one wave per row ----------------
__global__ __launch_bounds__(256) void k_ln(const float* __restrict__ x, const float* __restrict__ w,
                                            const float* __restrict__ b, u16* __restrict__ out) {
  int wave = threadIdx.x >> 6;
  int lane = threadIdx.x & 63;
  int r = blockIdx.x * 4 + wave;
  const float* xr = x + (size_t)r * DM + lane*8;
  float v[8];
  float4 a = *(const float4*)xr;
  float4 c = *(const float4*)(xr + 4);
  v[0]=a.x;v[1]=a.y;v[2]=a.z;v[3]=a.w;v[4]=c.x;v[5]=c.y;v[6]=c.z;v[7]=c.w;
  float s = 0.f, sq = 0.f;
  #pragma unroll
  for (int i=0;i<8;i++){ s += v[i]; sq += v[i]*v[i]; }
  #pragma unroll
  for (int m=1;m<64;m<<=1){ s += __shfl_xor(s, m, 64); sq += __shfl_xor(sq, m, 64); }
  float mean = s * (1.0f/DM);
  float var = sq * (1.0f/DM) - mean*mean;
  float rs = rsqrtf(var + LNEPS);
  int c0 = lane*8;
  u16x8 o;
  #pragma unroll
  for (int i=0;i<8;i++){
    float y = (v[i]-mean)*rs*w[c0+i] + b[c0+i];
    o[i] = f2bf(y);
  }
  *(u16x8*)(out + (size_t)r*DM + c0) = o;
}

// ---------------- GEMM: C[M,N] = A[M,K] * Bt[N,K]^T (+bias, gelu, residual) ----------------
// m97 structure: 128x128 tile, BK=64, linear LDS, global_load_lds(16B) staging,
// stage -> barrier -> MFMA -> barrier. XCD-chunked m-fastest block remap for B-panel L2 reuse.
#define GM_BIAS 1
#define GM_GELU 2
#define GM_RES  4
#define GM_BF16 8

template<int MODE>
__global__ __launch_bounds__(256, 2) void k_gemm_bt(
    const u16* __restrict__ A,    // [M,K] bf16
    const u16* __restrict__ Bt,   // [Nbt,K] bf16 (B transposed)
    const float* __restrict__ bias,
    void* __restrict__ C,         // f32 [M,N] (or bf16 if GM_BF16)
    int M, int N, int K, int Nbt) {
  __shared__ u16 As[128*64];
  __shared__ u16 Bs[128*64];
  int t = threadIdx.x;

  // ---- block remap: XCD-contiguous chunks, m-fastest inside each chunk ----
  unsigned gx = gridDim.x, gy = gridDim.y;
  unsigned nwg = gx * gy;
  unsigned bid = blockIdx.y * gx + blockIdx.x;
  unsigned u = bid;
  if ((nwg & 7u) == 0u) {
    unsigned chunk = nwg >> 3;
    u = (bid & 7u) * chunk + (bid >> 3);
  }
  unsigned mIdx = u % gy;           // gy = 32 (pow2) always
  unsigned nIdx = u / gy;
  int m0 = mIdx * 128, n0 = nIdx * 128;

  int w = t >> 6;
  int lane = t & 63;
  int wm = (w >> 1) * 64, wn = (w & 1) * 64;
  int lam = lane & 15, quad = lane >> 4;

  // ---- staging addresses: chunk c = t + i*256 -> row = (t>>3)+i*32, col8 = t&7 ----
  int srow = t >> 3;
  int scol = (t & 7) * 8;
  const u16* gA = A + (size_t)(m0 + srow) * K + scol;
  const u16* gB[4];
  #pragma unroll
  for (int i = 0; i < 4; i++) {
    int nr = n0 + srow + i*32;
    if (nr >= Nbt) nr = Nbt - 1;     // clamp: valid garbage, masked in epilogue
    gB[i] = Bt + (size_t)nr * K + scol;
  }
  u16* lA = &As[(size_t)t * 8];      // +i*256*8 per chunk
  u16* lB = &Bs[(size_t)t * 8];

  f32x4 zero = {0.f, 0.f, 0.f, 0.f};
  f32x4 acc[4][4];
  #pragma unroll
  for (int i=0;i<4;i++)
    #pragma unroll
    for (int j=0;j<4;j++) acc[i][j] = zero;

  int KT = K >> 6;
  for (int kt = 0; kt < KT; kt++) {
    int ko = kt * 64;
    #pragma unroll
    for (int i = 0; i < 4; i++) {
      gload16(gA + (size_t)i*32*K + ko, lA + i*256*8);
      gload16(gB[i] + ko,              lB + i*256*8);
    }
    __syncthreads();                  // compiler drains vmcnt before barrier
    #pragma unroll
    for (int s = 0; s < 2; s++) {
      bf16x8 af[4], bfv[4];
      #pragma unroll
      for (int i=0;i<4;i++) af[i]  = *(const bf16x8*)&As[(wm + i*16 + lam)*64 + s*32 + quad*8];
      #pragma unroll
      for (int i=0;i<4;i++) bfv[i] = *(const bf16x8*)&Bs[(wn + i*16 + lam)*64 + s*32 + quad*8];
      #pragma unroll
      for (int i=0;i<4;i++)
        #pragma unroll
        for (int j=0;j<4;j++)
          acc[i][j] = __builtin_amdgcn_mfma_f32_16x16x32_bf16(af[i], bfv[j], acc[i][j], 0, 0, 0);
    }
    __syncthreads();
  }

  // epilogue: D[row = quad*4+r][col = lam] per 16x16 tile (verified C/D layout)
  #pragma unroll
  for (int j=0;j<4;j++) {
    int col = n0 + wn + j*16 + lam;
    if (col < N) {
      float bs = (MODE & GM_BIAS) ? bias[col] : 0.0f;
      #pragma unroll
      for (int i=0;i<4;i++) {
        int rowb = m0 + wm + i*16 + quad*4;
        #pragma unroll
        for (int r=0;r<4;r++) {
          float v2 = acc[i][j][r] + bs;
          if (MODE & GM_GELU) v2 = 0.5f * v2 * (1.0f + erff(v2 * 0.70710678118f));
          size_t off = (size_t)(rowb + r) * N + col;
          if (MODE & GM_RES) {
            ((float*)C)[off] += v2;
          } else if (MODE & GM_BF16) {
            ((u16*)C)[off] = f2bf(v2);
          } else {
            ((float*)C)[off] = v2;
          }
        }
      }
    }
  }
}

// ---------------- flash attention: 1 wave per (b,h,16-query tile) ----------------
__global__ __launch_bounds__(64) void k_attn(const u16* __restrict__ qkv, u16* __restrict__ o) {
  int qt = blockIdx.x;               // 0..127
  int bh = blockIdx.y;               // 0..15
  int b = bh >> 3, h = bh & 7;
  int lane = threadIdx.x;
  int lam = lane & 15, quad = lane >> 4;
  int qbase = qt * 16;
  size_t base = (size_t)b * SS;

  __shared__ u16 Vs[32*72];
  __shared__ float Ps[16*36];

  // Q fragment (A layout: m=lam, k=quad*8+j, two k-steps of 32)
  const u16* qrow = qkv + (base + qbase + lam) * 1536 + h*64 + quad*8;
  bf16x8 qf0 = *(const bf16x8*)(qrow);
  bf16x8 qf1 = *(const bf16x8*)(qrow + 32);

  f32x4 zero = {0.f,0.f,0.f,0.f};
  float Mx[4], Ls[4];
  f32x4 oacc[4];
  #pragma unroll
  for (int r=0;r<4;r++){ Mx[r] = -1e30f; Ls[r] = 0.f; }
  #pragma unroll
  for (int d=0;d<4;d++) oacc[d] = zero;

  int nkb = ((qbase + 15) >> 5) + 1;
  for (int kb = 0; kb < nkb; kb++) {
    int ks = kb * 32;
    // QK^T -> S [16 q x 32 keys], two 16-key tiles
    f32x4 sacc[2] = {zero, zero};
    #pragma unroll
    for (int kt2 = 0; kt2 < 2; kt2++) {
      const u16* krow = qkv + (base + ks + kt2*16 + lam) * 1536 + 512 + h*64 + quad*8;
      bf16x8 kf0 = *(const bf16x8*)(krow);
      bf16x8 kf1 = *(const bf16x8*)(krow + 32);
      sacc[kt2] = __builtin_amdgcn_mfma_f32_16x16x32_bf16(qf0, kf0, sacc[kt2], 0,0,0);
      sacc[kt2] = __builtin_amdgcn_mfma_f32_16x16x32_bf16(qf1, kf1, sacc[kt2], 0,0,0);
    }
    // stage V [32 x 64] into LDS (coalesced 16B loads)
    {
      int vrow = lane >> 3, c8 = (lane & 7) * 8;
      #pragma unroll
      for (int i=0;i<4;i++) {
        uint4 vv = *(const uint4*)(qkv + (base + ks + vrow + i*8) * 1536 + 1024 + h*64 + c8);
        *(uint4*)&Vs[(vrow + i*8)*72 + c8] = vv;
      }
    }
    // mask + scale + online softmax (rows quad*4+r live in this quad's 16 lanes)
    float P[2][4];
    #pragma unroll
    for (int r=0;r<4;r++) {
      int q = qbase + quad*4 + r;
      float s0 = sacc[0][r] * 0.125f;
      float s1 = sacc[1][r] * 0.125f;
      if (ks + lam > q)       s0 = -1e30f;
      if (ks + 16 + lam > q)  s1 = -1e30f;
      float mx = fmaxf(s0, s1);
      #pragma unroll
      for (int m2=1;m2<16;m2<<=1) mx = fmaxf(mx, __shfl_xor(mx, m2, 64));
      float mn = fmaxf(Mx[r], mx);
      float alpha = __expf(Mx[r] - mn);
      float p0 = __expf(s0 - mn);
      float p1 = __expf(s1 - mn);
      float ps = p0 + p1;
      #pragma unroll
      for (int m2=1;m2<16;m2<<=1) ps += __shfl_xor(ps, m2, 64);
      Ls[r] = Ls[r]*alpha + ps;
      Mx[r] = mn;
      P[0][r] = p0; P[1][r] = p1;
      #pragma unroll
      for (int d=0;d<4;d++) oacc[d][r] *= alpha;
    }
    // P: C-layout -> LDS -> A-layout bf16
    #pragma unroll
    for (int kt2=0;kt2<2;kt2++)
      #pragma unroll
      for (int r=0;r<4;r++)
        Ps[(quad*4+r)*36 + kt2*16 + lam] = P[kt2][r];
    __syncthreads();
    bf16x8 pf;
    #pragma unroll
    for (int j=0;j<8;j++) pf[j] = (short)f2bf(Ps[lam*36 + quad*8 + j]);
    #pragma unroll
    for (int d=0;d<4;d++) {
      bf16x8 vf;
      #pragma unroll
      for (int j=0;j<8;j++) vf[j] = (short)Vs[(quad*8+j)*72 + d*16 + lam];
      oacc[d] = __builtin_amdgcn_mfma_f32_16x16x32_bf16(pf, vf, oacc[d], 0,0,0);
    }
    __syncthreads();
  }
  // write O (bf16), normalize by L
  #pragma unroll
  for (int d=0;d<4;d++)
    #pragma unroll
    for (int r=0;r<4;r++) {
      float val = oacc[d][r] / Ls[r];
      o[(base + qbase + quad*4 + r) * DM + h*64 + d*16 + lam] = f2bf(val);
    }
}

// ---------------- launch ----------------
extern "C" void kernel_launch(void* const* d_in, const int* in_sizes, int n_in,
                              void* d_out, int out_size, void* d_ws, size_t ws_size,
                              hipStream_t stream) {
  const int*   idx   = (const int*)d_in[0];
  const float* wte   = (const float*)d_in[1];
  const float* wpe   = (const float*)d_in[2];
  const float* ln1w  = (const float*)d_in[3];
  const float* ln1b  = (const float*)d_in[4];
  const float* Wqkv  = (const float*)d_in[5];
  const float* bqkv  = (const float*)d_in[6];
  const float* Wproj = (const float*)d_in[7];
  const float* bproj = (const float*)d_in[8];
  const float* ln2w  = (const float*)d_in[9];
  const float* ln2b  = (const float*)d_in[10];
  const float* Wfc   = (const float*)d_in[11];
  const float* bfc   = (const float*)d_in[12];
  const float* Wfc2  = (const float*)d_in[13];
  const float* bfc2  = (const float*)d_in[14];
  const float* lnfw  = (const float*)d_in[15];
  const float* lnfb  = (const float*)d_in[16];
  float* logits = (float*)d_out;

  char* ws = (char*)d_ws;
  auto alloc = [&](size_t bytes) { char* p = ws; ws += (bytes + 255) & ~(size_t)255; return p; };
  float* x    = (float*)alloc((size_t)RR*DM*4);
  u16* hbuf   = (u16*)alloc((size_t)RR*DM*2);
  u16* qkvb   = (u16*)alloc((size_t)RR*1536*2);
  u16* obuf   = (u16*)alloc((size_t)RR*DM*2);
  u16* ffbuf  = (u16*)alloc((size_t)RR*FFD*2);
  u16* wte_bf = (u16*)alloc((size_t)VSZ*DM*2);
  u16* WqkvT  = (u16*)alloc((size_t)NL*1536*DM*2);
  u16* WprojT = (u16*)alloc((size_t)NL*DM*DM*2);
  u16* WfcT   = (u16*)alloc((size_t)NL*FFD*DM*2);
  u16* Wfc2T  = (u16*)alloc((size_t)NL*DM*FFD*2);

  // one-time (per call) weight conversions
  long nwte = (long)VSZ * DM;
  k_convert<<<(int)((nwte/8 + 255)/256), 256, 0, stream>>>(wte, wte_bf, nwte);
  k_transpose_convert<<<dim3(1536/32, DM/32, NL), dim3(32,8), 0, stream>>>(Wqkv, WqkvT, DM, 1536);
  k_transpose_convert<<<dim3(DM/32, DM/32, NL),  dim3(32,8), 0, stream>>>(Wproj, WprojT, DM, DM);
  k_transpose_convert<<<dim3(FFD/32, DM/32, NL), dim3(32,8), 0, stream>>>(Wfc, WfcT, DM, FFD);
  k_transpose_convert<<<dim3(DM/32, FFD/32, NL), dim3(32,8), 0, stream>>>(Wfc2, Wfc2T, FFD, DM);

  k_embed<<<RR, 128, 0, stream>>>(idx, wte, wpe, x);

  for (int l = 0; l < NL; l++) {
    k_ln<<<RR/4, 256, 0, stream>>>(x, ln1w + l*DM, ln1b + l*DM, hbuf);
    k_gemm_bt<GM_BIAS|GM_BF16><<<dim3(1536/128, RR/128), 256, 0, stream>>>(
        hbuf, WqkvT + (size_t)l*1536*DM, bqkv + l*1536, qkvb, RR, 1536, DM, 1536);
    k_attn<<<dim3(SS/16, BB*NH), 64, 0, stream>>>(qkvb, obuf);
    k_gemm_bt<GM_BIAS|GM_RES><<<dim3(DM/128, RR/128), 256, 0, stream>>>(
        obuf, WprojT + (size_t)l*DM*DM, bproj + l*DM, x, RR, DM, DM, DM);
    k_ln<<<RR/4, 256, 0, stream>>>(x, ln2w + l*DM, ln2b + l*DM, hbuf);
    k_gemm_bt<GM_BIAS|GM_GELU|GM_BF16><<<dim3(FFD/128, RR/128), 256, 0, stream>>>(
        hbuf, WfcT + (size_t)l*FFD*DM, bfc + l*FFD, ffbuf, RR, FFD, DM, FFD);
    k_gemm_bt<GM_BIAS|GM_RES><<<dim3(DM/128, RR/128), 256, 0, stream>>>(
        ffbuf, Wfc2T + (size_t)l*DM*FFD, bfc2 + l*DM, x, RR, DM, FFD, DM);
  }
  k_ln<<<RR/4, 256, 0, stream>>>(x, lnfw, lnfb, hbuf);
  k_gemm_bt<0><<<dim3((VSZ+127)/128, RR/128), 256, 0, stream>>>(
      hbuf, wte_bf, nullptr, logits, RR, VSZ, DM, VSZ);
}